// Round 20
// baseline (744.900 us; speedup 1.0000x reference)
//
#include <hip/hip_runtime.h>
#include <hip/hip_bf16.h>
#include <math.h>

typedef unsigned int uint32;
typedef __attribute__((ext_vector_type(8))) short short8;
typedef __attribute__((ext_vector_type(4))) float f32x4;

#define TBINS 1024
#define RMAX  10.4f
#define BSHIFT 7              // 128 nodes per bucket (CSR build)
#define BDR    (1<<BSHIFT)

__device__ __forceinline__ uint32 pack_bf16(float a, float b){
  __hip_bfloat16 ba = __float2bfloat16(a);
  __hip_bfloat16 bb = __float2bfloat16(b);
  unsigned short ua = *reinterpret_cast<unsigned short*>(&ba);
  unsigned short ub = *reinterpret_cast<unsigned short*>(&bb);
  return (uint32)ua | ((uint32)ub << 16);
}
__device__ __forceinline__ float bf_lo(uint32 u){ return __uint_as_float(u << 16); }
__device__ __forceinline__ float bf_hi(uint32 u){ return __uint_as_float(u & 0xffff0000u); }

// ---------------- bucket-level histogram (both keys, one pass, LDS-staged) ----------------

__global__ __launch_bounds__(1024) void k_bcount(
    const int* __restrict__ esrc, const int* __restrict__ edst,
    int* __restrict__ gb1, int* __restrict__ gb2, int E){
  __shared__ int c1[1024], c2[1024];
  int tid = threadIdx.x;
  c1[tid] = 0; c2[tid] = 0;
  __syncthreads();
  int e0 = blockIdx.x * 8192;
  #pragma unroll
  for (int k=0;k<8;k++){
    int e = e0 + k*1024 + tid;
    if (e < E){
      atomicAdd(&c1[edst[e] >> BSHIFT], 1);
      atomicAdd(&c2[esrc[e] >> BSHIFT], 1);
    }
  }
  __syncthreads();
  if (c1[tid]) atomicAdd(&gb1[tid], c1[tid]);
  if (c2[tid]) atomicAdd(&gb2[tid], c2[tid]);
}

// ---------------- scan bucket counts -> bucket offsets + cursors (one block) ----------------

__global__ __launch_bounds__(1024) void k_bscan(
    const int* __restrict__ gb1, const int* __restrict__ gb2,
    int* __restrict__ boff1, int* __restrict__ boff2,
    int* __restrict__ gcur1, int* __restrict__ gcur2,
    int* __restrict__ offsets, int* __restrict__ off2,
    int N, int E, int NBUCK){
  __shared__ int sm[1024];
  int tid = threadIdx.x;
  int v = (tid < NBUCK) ? gb1[tid] : 0;
  sm[tid] = v; __syncthreads();
  for (int off=1; off<1024; off<<=1){
    int t = (tid >= off) ? sm[tid-off] : 0;
    __syncthreads();
    sm[tid] += t;
    __syncthreads();
  }
  if (tid < NBUCK){ int o = sm[tid]-v; boff1[tid] = o; gcur1[tid] = o; }
  __syncthreads();
  int v2 = (tid < NBUCK) ? gb2[tid] : 0;
  sm[tid] = v2; __syncthreads();
  for (int off=1; off<1024; off<<=1){
    int t = (tid >= off) ? sm[tid-off] : 0;
    __syncthreads();
    sm[tid] += t;
    __syncthreads();
  }
  if (tid < NBUCK){ int o = sm[tid]-v2; boff2[tid] = o; gcur2[tid] = o; }
  if (tid == 0){
    boff1[NBUCK] = E; boff2[NBUCK] = E;
    offsets[N] = E;   off2[N] = E;
  }
}

// ---------------- counting-sort pass A: BOTH keys in one sweep ----------------

__global__ __launch_bounds__(1024) void k_binA2(
    const int* __restrict__ esrc, const int* __restrict__ edst,
    int* __restrict__ gcur1, int* __restrict__ gcur2,
    int2* __restrict__ pair1, int2* __restrict__ pair2, int E, int NBUCK){
  __shared__ int cnt1[1024], run1[1024];
  __shared__ int cnt2[1024], run2[1024];
  int tid = threadIdx.x;
  int e0 = blockIdx.x * 8192;
  cnt1[tid] = 0; cnt2[tid] = 0;
  __syncthreads();
  #pragma unroll
  for (int k=0;k<8;k++){
    int e = e0 + k*1024 + tid;
    if (e < E){
      atomicAdd(&cnt1[edst[e] >> BSHIFT], 1);
      atomicAdd(&cnt2[esrc[e] >> BSHIFT], 1);
    }
  }
  __syncthreads();
  if (tid < NBUCK){
    if (cnt1[tid] > 0) run1[tid] = atomicAdd(&gcur1[tid], cnt1[tid]);
    if (cnt2[tid] > 0) run2[tid] = atomicAdd(&gcur2[tid], cnt2[tid]);
  }
  __syncthreads();
  #pragma unroll
  for (int k=0;k<8;k++){
    int e = e0 + k*1024 + tid;
    if (e < E){
      int s = esrc[e], d = edst[e];
      int p1 = atomicAdd(&run1[d >> BSHIFT], 1);
      int2 pr1; pr1.x = s; pr1.y = d;
      pair1[p1] = pr1;
      int p2 = atomicAdd(&run2[s >> BSHIFT], 1);
      int2 pr2; pr2.x = d; pr2.y = s;
      pair2[p2] = pr2;
    }
  }
}

// ---------------- counting-sort pass B: per-bucket local offsets + CSR fill ----------------

__global__ __launch_bounds__(256) void k_binB2(
    const int2* __restrict__ pair, const int* __restrict__ boff,
    int* __restrict__ offsets, int* __restrict__ csr_out, int N){
  __shared__ int cnt[BDR];
  __shared__ int scn[BDR];
  int base = blockIdx.x << BSHIFT;
  int hi = base + BDR; if (hi > N) hi = N;
  int nloc = hi - base;
  if (nloc <= 0) return;
  int tid = threadIdx.x;
  if (tid < BDR) cnt[tid] = 0;
  __syncthreads();
  int p0 = boff[blockIdx.x], p1 = boff[blockIdx.x+1];
  for (int p = p0 + tid; p < p1; p += 256) atomicAdd(&cnt[pair[p].y - base], 1);
  __syncthreads();
  int val = (tid < BDR) ? cnt[tid] : 0;
  if (tid < BDR) scn[tid] = val;
  __syncthreads();
  for (int off=1; off<BDR; off<<=1){
    int t = (tid >= off && tid < BDR) ? scn[tid-off] : 0;
    __syncthreads();
    if (tid < BDR) scn[tid] += t;
    __syncthreads();
  }
  if (tid < nloc){
    int o = p0 + scn[tid] - val;
    offsets[base + tid] = o;
    cnt[tid] = o;
  }
  __syncthreads();
  for (int p = p0 + tid; p < p1; p += 256){
    int2 pr = pair[p];
    int slot = atomicAdd(&cnt[pr.y - base], 1);
    csr_out[slot] = pr.x;
  }
}

// ---------------- pack pos+type into one float4 ----------------

__global__ void k_pack(const float* __restrict__ pos, const int* __restrict__ types,
                       float4* __restrict__ ptyp, int N){
  int i = blockIdx.x*256 + threadIdx.x;
  if (i >= N) return;
  float4 f; f.x = pos[3*i]; f.y = pos[3*i+1]; f.z = pos[3*i+2]; f.w = __int_as_float(types[i]);
  ptyp[i] = f;
}

// ---------------- radial-MLP evaluation (builder only) ----------------

__device__ __forceinline__ void radial_mlp(
    float r, int td, int ts, const float* sEmb,
    const float* sW1, const float* sW2, float* w_out /*9*/){
  float ee[18];
  #pragma unroll
  for (int i=0;i<4;i++){ ee[i] = sEmb[td*4+i]; ee[4+i] = sEmb[ts*4+i]; }
  float rm = fmaxf(r, 1e-9f);
  float inv = 1.f/rm;
  float xx = r * 0.2f;
  float x2v = xx*xx, x3v = x2v*xx, x6 = x3v*x3v, x7 = x6*xx, x8 = x7*xx;
  float env = 1.f - 28.f*x6 + 48.f*x7 - 21.f*x8;
  const float bc = 0.6324555320336759f;
  float pref = bc * env * inv;
  const float PI = 3.14159265358979323846f;
  float s1, cth;
  __sincosf(PI*xx, &s1, &cth);
  float two_c = 2.f*cth;
  float sp = 0.f, sc = s1;
  ee[8] = pref * sc;
  #pragma unroll
  for (int n=2;n<=10;n++){
    float sn = two_c*sc - sp;
    sp = sc; sc = sn;
    ee[7+n] = pref * sc;
  }
  float h[10];
  #pragma unroll
  for (int j=0;j<10;j++){
    float a = 0.f;
    #pragma unroll
    for (int k=0;k<18;k++) a = fmaf(ee[k], sW1[k*10+j], a);
    h[j] = fmaxf(a, 0.f);
  }
  #pragma unroll
  for (int sj=0;sj<9;sj++){
    float a = 0.f;
    #pragma unroll
    for (int j=0;j<10;j++) a = fmaf(h[j], sW2[j*9+sj], a);
    w_out[sj] = a;
  }
}

// ---------------- merged table: 32 u32/rec = {w1(v,d)x9, w2(v,d)x9, w3(v,d)x9, pad5} ----------------

__global__ __launch_bounds__(256) void k_mktab(
    const float* __restrict__ embed,
    const float* __restrict__ w1a, const float* __restrict__ w2a,
    const float* __restrict__ w1b, const float* __restrict__ w2b,
    const float* __restrict__ w1c, const float* __restrict__ w2c,
    uint32* __restrict__ tab){
  __shared__ float sEmb[16];
  __shared__ float sW1a[180], sW2a[90], sW1b[180], sW2b[90], sW1c[180], sW2c[90];
  int t = threadIdx.x;
  if (t < 16) sEmb[t] = embed[t];
  if (t < 180){ sW1a[t] = w1a[t]; sW1b[t] = w1b[t]; sW1c[t] = w1c[t]; }
  if (t < 90){  sW2a[t] = w2a[t]; sW2b[t] = w2b[t]; sW2c[t] = w2c[t]; }
  __syncthreads();
  int gid = blockIdx.x*256 + t;
  if (gid >= 16*TBINS) return;
  int combo = gid / TBINS, bin = gid - combo*TBINS;
  int td = combo >> 2, ts = combo & 3;
  const float dR = RMAX / TBINS;
  float r0 = bin*dR, r1 = r0 + dR;
  float a0[9], a1[9], b0[9], b1[9], c0[9], c1[9];
  radial_mlp(r0, td, ts, sEmb, sW1a, sW2a, a0);
  radial_mlp(r1, td, ts, sEmb, sW1a, sW2a, a1);
  radial_mlp(r0, td, ts, sEmb, sW1b, sW2b, b0);
  radial_mlp(r1, td, ts, sEmb, sW1b, sW2b, b1);
  radial_mlp(r0, td, ts, sEmb, sW1c, sW2c, c0);
  radial_mlp(r1, td, ts, sEmb, sW1c, sW2c, c1);
  uint32* rec = tab + (size_t)gid*32;
  #pragma unroll
  for (int s=0;s<9;s++){
    rec[s]    = pack_bf16(a0[s], a1[s]-a0[s]);
    rec[9+s]  = pack_bf16(b0[s], b1[s]-b0[s]);
    rec[18+s] = pack_bf16(c0[s], c1[s]-c0[s]);
  }
  #pragma unroll
  for (int s=27;s<32;s++) rec[s] = 0u;
}

// ---------------- layer 1+2 edge pass: Z->x1, bf16 shw2 (SoA planes) ----------------

__global__ __launch_bounds__(256) void k_layer12t(
    const int* __restrict__ offsets, const int* __restrict__ csr_src,
    const float4* __restrict__ ptyp, const float* __restrict__ embed,
    const uint32* __restrict__ tab, const float* __restrict__ tp1,
    float* __restrict__ x1, uint32* __restrict__ shwb, int N, int E){
  __shared__ float sT[36*92];
  __shared__ float sEmb[16];
  int t = threadIdx.x;
  if (t < 16) sEmb[t] = embed[t];
  for (int i=t; i<36*92; i+=256) sT[i] = tp1[i]*0.25f;
  __syncthreads();
  int gid = blockIdx.x*256 + t;
  int n = gid >> 2, q = gid & 3;
  if (n >= N) return;
  float4 fd = ptyp[n];
  float dx = fd.x, dy = fd.y, dz = fd.z;
  int td = __float_as_int(fd.w);
  const float c1 = 1.7320508075688772f, c2 = 3.872983346207417f, c2b = 1.118033988749895f;
  const float invD = (float)TBINS / RMAX;
  float Z[36];
  #pragma unroll
  for (int i=0;i<36;i++) Z[i]=0.f;
  int b0 = offsets[n], b1 = offsets[n+1];
  for (int j=b0+q; j<b1; j+=4){
    int s = csr_src[j];
    float4 fs = ptyp[s];
    float px = dx - fs.x, py = dy - fs.y, pz = dz - fs.z;
    int ts_ = __float_as_int(fs.w);
    float r = sqrtf(px*px + py*py + pz*pz);
    float inv = 1.f/fmaxf(r, 1e-9f);
    float ux = px*inv, uy = py*inv, uz = pz*inv;
    float sh[9];
    sh[0]=1.f; sh[1]=c1*uy; sh[2]=c1*uz; sh[3]=c1*ux;
    sh[4]=c2*ux*uy; sh[5]=c2*uy*uz; sh[6]=c2b*(3.f*uz*uz-1.f); sh[7]=c2*ux*uz;
    sh[8]=0.5f*c2*(ux*ux-uy*uy);
    float tt = r * invD;
    int bb = (int)tt; bb = (bb > TBINS-1) ? TBINS-1 : bb;
    float frac = tt - (float)bb;
    const uint32* rec = tab + ((size_t)((td*4+ts_)*TBINS + bb))*32;
    uint32 R[20];
    #pragma unroll
    for (int i=0;i<5;i++) *(uint4*)&R[i*4] = *(const uint4*)(rec + i*4);
    float x0[4];
    #pragma unroll
    for (int i=0;i<4;i++) x0[i] = sEmb[ts_*4+i];
    float sw2[9];
    #pragma unroll
    for (int sj=0;sj<9;sj++){
      uint32 ua = R[sj], ub = R[9+sj];
      float w1v = fmaf(frac, bf_hi(ua), bf_lo(ua));
      float w2v = fmaf(frac, bf_hi(ub), bf_lo(ub));
      float s1v = sh[sj]*w1v;
      sw2[sj] = sh[sj]*w2v;
      #pragma unroll
      for (int i=0;i<4;i++) Z[sj*4+i] = fmaf(s1v, x0[i], Z[sj*4+i]);
    }
    shwb[j]             = pack_bf16(sw2[0],sw2[1]);
    shwb[(size_t)E+j]   = pack_bf16(sw2[2],sw2[3]);
    shwb[(size_t)2*E+j] = pack_bf16(sw2[4],sw2[5]);
    shwb[(size_t)3*E+j] = pack_bf16(sw2[6],sw2[7]);
    shwb[(size_t)4*E+j] = pack_bf16(sw2[8],0.f);
  }
  #pragma unroll
  for (int m=1; m<=2; m<<=1){
    #pragma unroll
    for (int i=0;i<36;i++) Z[i] += __shfl_xor(Z[i], m, 4);
  }
  float* xo = x1 + (size_t)n*76;
  int gi_prev = -1; float ga = 0.f;
  for (int cc=q*19; cc<q*19+19; cc++){
    float v;
    if (cc < 12){
      float y = 0.f;
      #pragma unroll
      for (int p=0;p<36;p++) y = fmaf(Z[p], sT[p*92+cc], y);
      v = (cc<4) ? (fmaxf(y,0.f) + sEmb[td*4+cc]) : fabsf(y);
    } else {
      int j = cc - 12;
      int gi = (j<24) ? (j/3) : (8 + (j-24)/5);
      if (gi != gi_prev){
        float gy = 0.f;
        #pragma unroll
        for (int p=0;p<36;p++) gy = fmaf(Z[p], sT[p*92+12+gi], gy);
        ga = (gi<4 || (gi>=8 && gi<12)) ? fmaxf(gy,0.f) : tanhf(gy);
        gi_prev = gi;
      }
      float y = 0.f;
      #pragma unroll
      for (int p=0;p<36;p++) y = fmaf(Z[p], sT[p*92+28+j], y);
      v = y*ga;
    }
    xo[cc] = v;
  }
}

// ---------------- cast x1 -> bf16 pairs ----------------

__global__ void k_cast(const float* __restrict__ x1, uint32* __restrict__ x1b, int n38){
  int i = blockIdx.x*256 + threadIdx.x;
  if (i >= n38) return;
  float2 f = *(const float2*)&x1[(size_t)i*2];
  x1b[i] = pack_bf16(f.x, f.y);
}

// ---------------- W transpose-pack for MFMA ----------------

__global__ void k_wprep2(const float* __restrict__ tp2, unsigned short* __restrict__ Wt){
  int q = blockIdx.x*256 + threadIdx.x;
  if (q >= 22*96*32) return;
  int kin = q & 31;
  int rest = q >> 5;
  int col = rest % 96, s = rest / 96;
  int k = s*32 + kin;
  float v = (k < 684 && col < 92) ? tp2[k*92+col]*0.25f : 0.f;
  __hip_bfloat16 b = __float2bfloat16(v);
  Wt[q] = *reinterpret_cast<unsigned short*>(&b);
}

// ---------------- FUSED layer 2: conv (Z in LDS) + MFMA GEMM + gate + residual + A ----------------
// Block owns 32 dest nodes. Phase 1: threads accumulate Z rows into a bf16 LDS
// tile [32][356 u32] (row pad 356 -> 2-way max bank aliasing on frag reads).
// Phase 2: 4 waves MFMA from LDS A-frags x L2-hot Wt. Phase 3: epilogue.

__global__ __launch_bounds__(256) void k_conv2gemm(
    const int* __restrict__ offsets, const int* __restrict__ csr_src,
    const uint32* __restrict__ shwb, const uint32* __restrict__ x1b,
    const unsigned short* __restrict__ Wt, const float* __restrict__ x1,
    const float* __restrict__ tp3, float* __restrict__ A, int N, int E){
  __shared__ __align__(16) uint32 Zl[32*356];
  __shared__ float lw[32][100];
  __shared__ float tl3[684];
  int t = threadIdx.x;
  int n0 = blockIdx.x*32;
  int nloc = N - n0; if (nloc > 32) nloc = 32;
  if (nloc <= 0) return;
  for (int i=t;i<684;i+=256) tl3[i] = tp3[i]*0.25f;
  __syncthreads();
  // ---- phase 1: conv into LDS ----
  for (int p = t; p < nloc*38; p += 256){
    int dg = p/38;
    int u = p - dg*38;
    int d = n0 + dg;
    float z[9], zb[9];
    #pragma unroll
    for (int s=0;s<9;s++){ z[s]=0.f; zb[s]=0.f; }
    int b0 = offsets[d], b1 = offsets[d+1];
    for (int j=b0;j<b1;j++){
      int sn = csr_src[j];
      uint32 xv = x1b[(size_t)sn*38 + u];
      float xa = bf_lo(xv), xb = bf_hi(xv);
      uint32 a0 = shwb[j];
      uint32 a1 = shwb[(size_t)E+j];
      uint32 a2 = shwb[(size_t)2*E+j];
      uint32 a3 = shwb[(size_t)3*E+j];
      uint32 a4 = shwb[(size_t)4*E+j];
      float w[9];
      w[0]=bf_lo(a0); w[1]=bf_hi(a0); w[2]=bf_lo(a1); w[3]=bf_hi(a1);
      w[4]=bf_lo(a2); w[5]=bf_hi(a2); w[6]=bf_lo(a3); w[7]=bf_hi(a3); w[8]=bf_lo(a4);
      #pragma unroll
      for (int s=0;s<9;s++){
        z[s]  = fmaf(w[s], xa, z[s]);
        zb[s] = fmaf(w[s], xb, zb[s]);
      }
    }
    uint32* zr = &Zl[dg*356];
    #pragma unroll
    for (int s=0;s<9;s++) zr[s*38+u] = pack_bf16(z[s], zb[s]);
    if (u < 10) zr[342+u] = 0u;
  }
  // zero Z rows beyond nloc (MFMA reads them; results discarded but keep finite)
  for (int i = nloc*356 + t; i < 32*356; i += 256) Zl[i] = 0u;
  __syncthreads();
  // ---- phase 2: MFMA. wave w: row-half h=(w&1), col-halfgroup ch=(w>>1) (3 tiles) ----
  int w = t >> 6, l = t & 63;
  int h = w & 1, chg = w >> 1;
  int lrow = l & 15, lk = l >> 4;
  const uint32* arow = &Zl[(h*16 + lrow)*356 + lk*4];
  const short8* bb = (const short8*)Wt;
  int boff = lrow*4 + lk;
  f32x4 acc[3];
  #pragma unroll
  for (int ct=0;ct<3;ct++) acc[ct] = (f32x4){0.f,0.f,0.f,0.f};
  for (int s=0;s<22;s++){
    short8 af = *(const short8*)(arow + s*16);
    #pragma unroll
    for (int ct=0;ct<3;ct++){
      int ctg = chg*3 + ct;
      short8 bf = bb[(s*96 + ctg*16)*4 + boff];
      acc[ct] = __builtin_amdgcn_mfma_f32_16x16x32_bf16(af, bf, acc[ct], 0, 0, 0);
    }
  }
  __syncthreads();           // Zl reads done before lw overwrite? lw separate buffer; sync for safety of phase ordering
  #pragma unroll
  for (int ct=0;ct<3;ct++){
    int ctg = chg*3 + ct;
    #pragma unroll
    for (int i=0;i<4;i++)
      lw[h*16 + lk*4 + i][ctg*16 + lrow] = acc[ct][i];
  }
  __syncthreads();
  // ---- phase 3: epilogue (threads 0..127), gate + residual + A-dot ----
  int m = t>>2, q = t&3;
  float pA[9];
  #pragma unroll
  for (int s=0;s<9;s++) pA[s]=0.f;
  int node = n0 + m;
  bool act = (m < nloc) && (t < 128);
  if (act){
    const float* xr = x1 + (size_t)node*76;
    for (int cc=q*19; cc<q*19+19; cc++){
      float v;
      if (cc < 12){
        float y = lw[m][cc];
        v = (cc<4) ? fmaxf(y,0.f) : fabsf(y);
      } else {
        int j = cc-12;
        int gi = (j<24) ? (j/3) : (8 + (j-24)/5);
        float gy = lw[m][12+gi];
        float ga = (gi<4 || (gi>=8 && gi<12)) ? fmaxf(gy,0.f) : tanhf(gy);
        v = lw[m][28+j]*ga;
      }
      float xv = v + xr[cc];
      #pragma unroll
      for (int s=0;s<9;s++) pA[s] = fmaf(xv, tl3[s*76+cc], pA[s]);
    }
  }
  #pragma unroll
  for (int off=1; off<=2; off<<=1){
    #pragma unroll
    for (int s=0;s<9;s++) pA[s] += __shfl_xor(pA[s], off, 4);
  }
  if (act && q == 0){
    float* Ar = A + (size_t)node*16;
    float4 w0 = {pA[0],pA[1],pA[2],pA[3]};
    float4 w1 = {pA[4],pA[5],pA[6],pA[7]};
    *(float4*)Ar = w0;
    *(float4*)(Ar+4) = w1;
    Ar[8] = pA[8];
  }
}

// ---------------- layer 3: G[n] over src-CSR (L2-resident gathers only) ----------------

__global__ __launch_bounds__(256) void k_g3t(
    const int* __restrict__ off2, const int* __restrict__ csr2_dst,
    const float4* __restrict__ ptyp, const uint32* __restrict__ tab,
    float* __restrict__ G, int N){
  int gid = blockIdx.x*256 + threadIdx.x;
  int n = gid >> 2, q = gid & 3;
  if (n >= N) return;
  float acc[9];
  #pragma unroll
  for (int s=0;s<9;s++) acc[s]=0.f;
  float4 fs = ptyp[n];
  float sx = fs.x, sy = fs.y, sz = fs.z;
  int ts_ = __float_as_int(fs.w);
  const float c1 = 1.7320508075688772f, c2 = 3.872983346207417f, c2b = 1.118033988749895f;
  const float invD = (float)TBINS / RMAX;
  int b0 = off2[n], b1 = off2[n+1];
  for (int j=b0+q; j<b1; j+=4){
    int d = csr2_dst[j];
    float4 fdd = ptyp[d];
    float px = fdd.x-sx, py = fdd.y-sy, pz = fdd.z-sz;
    int td_ = __float_as_int(fdd.w);
    float r = sqrtf(px*px + py*py + pz*pz);
    float inv = 1.f/fmaxf(r, 1e-9f);
    float ux = px*inv, uy = py*inv, uz = pz*inv;
    float sh[9];
    sh[0]=1.f; sh[1]=c1*uy; sh[2]=c1*uz; sh[3]=c1*ux;
    sh[4]=c2*ux*uy; sh[5]=c2*uy*uz; sh[6]=c2b*(3.f*uz*uz-1.f); sh[7]=c2*ux*uz;
    sh[8]=0.5f*c2*(ux*ux-uy*uy);
    float tt = r * invD;
    int bb = (int)tt; bb = (bb > TBINS-1) ? TBINS-1 : bb;
    float frac = tt - (float)bb;
    const uint32* rec = tab + ((size_t)((td_*4+ts_)*TBINS + bb))*32;
    uint32 R[12];
    #pragma unroll
    for (int i=0;i<3;i++) *(uint4*)&R[i*4] = *(const uint4*)(rec + 16 + i*4);
    #pragma unroll
    for (int sj=0;sj<9;sj++){
      uint32 u = R[2+sj];
      float w = fmaf(frac, bf_hi(u), bf_lo(u));
      acc[sj] = fmaf(sh[sj], w, acc[sj]);
    }
  }
  #pragma unroll
  for (int off=2; off>0; off>>=1){
    #pragma unroll
    for (int s=0;s<9;s++) acc[s] += __shfl_down(acc[s], off, 4);
  }
  if (q == 0){
    float* gr = G + (size_t)n*12;
    float4 w0 = {acc[0],acc[1],acc[2],acc[3]};
    float4 w1 = {acc[4],acc[5],acc[6],acc[7]};
    *(float4*)gr = w0;
    *(float4*)(gr+4) = w1;
    gr[8] = acc[8];
  }
}

// ---------------- layer 3 finish: streaming dot(G, A) ----------------

__global__ __launch_bounds__(256) void k_finalG(
    const float* __restrict__ G, const float* __restrict__ A,
    float* __restrict__ out, int N){
  int n = blockIdx.x*256 + threadIdx.x;
  float part = 0.f;
  if (n < N){
    const float* gr = G + (size_t)n*12;
    const float* Ar = A + (size_t)n*16;
    float4 g0 = *(const float4*)gr, g1 = *(const float4*)(gr+4);
    float4 a0 = *(const float4*)Ar, a1 = *(const float4*)(Ar+4);
    part = g0.x*a0.x + g0.y*a0.y + g0.z*a0.z + g0.w*a0.w
         + g1.x*a1.x + g1.y*a1.y + g1.z*a1.z + g1.w*a1.w
         + gr[8]*Ar[8];
  }
  #pragma unroll
  for (int off=32; off>0; off>>=1) part += __shfl_down(part, off, 64);
  if ((threadIdx.x & 63) == 0) atomicAdd(out, part);
}

// ---------------- launch ----------------

extern "C" void kernel_launch(void* const* d_in, const int* in_sizes, int n_in,
                              void* d_out, int out_size, void* d_ws, size_t ws_size,
                              hipStream_t stream){
  const int*   types = (const int*)d_in[0];
  const float* pos   = (const float*)d_in[1];
  const int*   esrc  = (const int*)d_in[2];
  const int*   edst  = (const int*)d_in[3];
  const float* embed = (const float*)d_in[4];
  const float* m1w1=(const float*)d_in[5],  *m1w2=(const float*)d_in[6],  *tp1=(const float*)d_in[7];
  const float* m2w1=(const float*)d_in[8],  *m2w2=(const float*)d_in[9],  *tp2=(const float*)d_in[10];
  const float* m3w1=(const float*)d_in[11], *m3w2=(const float*)d_in[12], *tp3=(const float*)d_in[13];
  int N = in_sizes[0];
  int E = in_sizes[2];
  float* out = (float*)d_out;

  char* wsb = (char*)d_ws; size_t off = 0;
  auto alloc = [&](size_t b)->char*{ char* p = wsb + off; off = (off + b + 255) & ~(size_t)255; return p; };
  float*  x1      = (float*)alloc((size_t)N*76*sizeof(float));
  uint32* x1b     = (uint32*)alloc((size_t)N*38*sizeof(uint32));
  float4* ptyp    = (float4*)alloc((size_t)N*sizeof(float4));
  uint32* shwb    = (uint32*)alloc((size_t)E*5*sizeof(uint32));
  int*    csr_src = (int*)alloc((size_t)E*sizeof(int));
  int*    csr2_dst= (int*)alloc((size_t)E*sizeof(int));
  int2*   pair1   = (int2*)alloc((size_t)E*sizeof(int2));
  int2*   pair2   = (int2*)alloc((size_t)E*sizeof(int2));
  int*    offsets = (int*)alloc((size_t)(N+1)*sizeof(int));
  int*    off2    = (int*)alloc((size_t)(N+1)*sizeof(int));
  int*    gb1     = (int*)alloc(1024*sizeof(int));
  int*    gb2     = (int*)alloc(1024*sizeof(int));
  int*    boff1   = (int*)alloc(1025*sizeof(int));
  int*    boff2   = (int*)alloc(1025*sizeof(int));
  int*    gcur1   = (int*)alloc(1024*sizeof(int));
  int*    gcur2   = (int*)alloc(1024*sizeof(int));
  unsigned short* Wt = (unsigned short*)alloc((size_t)22*96*32*sizeof(unsigned short));
  float*  A       = (float*)alloc((size_t)N*16*sizeof(float));
  float*  G       = (float*)alloc((size_t)N*12*sizeof(float));
  uint32* tab     = (uint32*)alloc((size_t)16*TBINS*32*sizeof(uint32));

  hipMemsetAsync(gb1, 0, 2048*sizeof(int), stream);   // gb1 | gb2 contiguous
  hipMemsetAsync(out, 0, sizeof(float), stream);

  int nbN = (N+255)/256;
  int nbT = (16*TBINS+255)/256;
  int NBUCK = (N + BDR - 1) >> BSHIFT;
  int nbC = (E+8191)/8192;
  k_pack<<<nbN,256,0,stream>>>(pos, types, ptyp, N);
  k_mktab<<<nbT,256,0,stream>>>(embed, m1w1, m1w2, m2w1, m2w2, m3w1, m3w2, tab);
  // bucket histogram (both keys) + bucket scan
  k_bcount<<<nbC,1024,0,stream>>>(esrc, edst, gb1, gb2, E);
  k_bscan<<<1,1024,0,stream>>>(gb1, gb2, boff1, boff2, gcur1, gcur2,
                               offsets, off2, N, E, NBUCK);
  // both sorts: one sweep writes both pair arrays
  k_binA2<<<nbC,1024,0,stream>>>(esrc, edst, gcur1, gcur2, pair1, pair2, E, NBUCK);
  k_binB2<<<NBUCK,256,0,stream>>>(pair1, boff1, offsets, csr_src, N);
  k_binB2<<<NBUCK,256,0,stream>>>(pair2, boff2, off2, csr2_dst, N);

  k_wprep2<<<(22*96*32+255)/256,256,0,stream>>>(tp2, Wt);

  // layer 3 geometry part (independent of layers 1-2)
  k_g3t<<<(4*N+255)/256,256,0,stream>>>(off2, csr2_dst, ptyp, tab, G, N);

  // layer 1 + layer-2 shw (single fused edge pass, merged table, SoA shwb)
  k_layer12t<<<(4*N+255)/256,256,0,stream>>>(offsets, csr_src, ptyp, embed,
                                             tab, tp1, x1, shwb, N, E);
  k_cast<<<(N*38+255)/256,256,0,stream>>>(x1, x1b, N*38);

  // layer 2 fused: conv->LDS->MFMA->epilogue (no Z2u round-trip)
  k_conv2gemm<<<(N+31)/32,256,0,stream>>>(offsets, csr_src, shwb, x1b,
                                          Wt, x1, tp3, A, N, E);

  // layer 3 finish: streaming dot
  k_finalG<<<nbN,256,0,stream>>>(G, A, out, N);
}

// Round 21
// 493.490 us; speedup vs baseline: 1.5095x; 1.5095x over previous
//
#include <hip/hip_runtime.h>
#include <hip/hip_bf16.h>
#include <math.h>

typedef unsigned int uint32;
typedef __attribute__((ext_vector_type(8))) short short8;
typedef __attribute__((ext_vector_type(4))) float f32x4;

#define TBINS 1024
#define RMAX  10.4f
#define BSHIFT 7              // 128 nodes per bucket (CSR build)
#define BDR    (1<<BSHIFT)

__device__ __forceinline__ uint32 pack_bf16(float a, float b){
  __hip_bfloat16 ba = __float2bfloat16(a);
  __hip_bfloat16 bb = __float2bfloat16(b);
  unsigned short ua = *reinterpret_cast<unsigned short*>(&ba);
  unsigned short ub = *reinterpret_cast<unsigned short*>(&bb);
  return (uint32)ua | ((uint32)ub << 16);
}
__device__ __forceinline__ float bf_lo(uint32 u){ return __uint_as_float(u << 16); }
__device__ __forceinline__ float bf_hi(uint32 u){ return __uint_as_float(u & 0xffff0000u); }

// ---------------- bucket-level histogram (both keys, one pass, LDS-staged) ----------------

__global__ __launch_bounds__(1024) void k_bcount(
    const int* __restrict__ esrc, const int* __restrict__ edst,
    int* __restrict__ gb1, int* __restrict__ gb2, int E){
  __shared__ int c1[1024], c2[1024];
  int tid = threadIdx.x;
  c1[tid] = 0; c2[tid] = 0;
  __syncthreads();
  int e0 = blockIdx.x * 8192;
  #pragma unroll
  for (int k=0;k<8;k++){
    int e = e0 + k*1024 + tid;
    if (e < E){
      atomicAdd(&c1[edst[e] >> BSHIFT], 1);
      atomicAdd(&c2[esrc[e] >> BSHIFT], 1);
    }
  }
  __syncthreads();
  if (c1[tid]) atomicAdd(&gb1[tid], c1[tid]);
  if (c2[tid]) atomicAdd(&gb2[tid], c2[tid]);
}

// ---------------- scan bucket counts -> bucket offsets + cursors (one block) ----------------

__global__ __launch_bounds__(1024) void k_bscan(
    const int* __restrict__ gb1, const int* __restrict__ gb2,
    int* __restrict__ boff1, int* __restrict__ boff2,
    int* __restrict__ gcur1, int* __restrict__ gcur2,
    int* __restrict__ offsets, int* __restrict__ off2,
    int N, int E, int NBUCK){
  __shared__ int sm[1024];
  int tid = threadIdx.x;
  int v = (tid < NBUCK) ? gb1[tid] : 0;
  sm[tid] = v; __syncthreads();
  for (int off=1; off<1024; off<<=1){
    int t = (tid >= off) ? sm[tid-off] : 0;
    __syncthreads();
    sm[tid] += t;
    __syncthreads();
  }
  if (tid < NBUCK){ int o = sm[tid]-v; boff1[tid] = o; gcur1[tid] = o; }
  __syncthreads();
  int v2 = (tid < NBUCK) ? gb2[tid] : 0;
  sm[tid] = v2; __syncthreads();
  for (int off=1; off<1024; off<<=1){
    int t = (tid >= off) ? sm[tid-off] : 0;
    __syncthreads();
    sm[tid] += t;
    __syncthreads();
  }
  if (tid < NBUCK){ int o = sm[tid]-v2; boff2[tid] = o; gcur2[tid] = o; }
  if (tid == 0){
    boff1[NBUCK] = E; boff2[NBUCK] = E;
    offsets[N] = E;   off2[N] = E;
  }
}

// ---------------- counting-sort pass A ----------------

__global__ __launch_bounds__(1024) void k_binA(
    const int* __restrict__ key, const int* __restrict__ pay,
    int* __restrict__ gcur, int2* __restrict__ pair, int E, int NBUCK){
  __shared__ int cnt[1024];
  __shared__ int run[1024];
  int tid = threadIdx.x;
  int e0 = blockIdx.x * 8192;
  cnt[tid] = 0;
  __syncthreads();
  #pragma unroll
  for (int k=0;k<8;k++){
    int e = e0 + k*1024 + tid;
    if (e < E) atomicAdd(&cnt[key[e] >> BSHIFT], 1);
  }
  __syncthreads();
  if (tid < NBUCK && cnt[tid] > 0) run[tid] = atomicAdd(&gcur[tid], cnt[tid]);
  __syncthreads();
  #pragma unroll
  for (int k=0;k<8;k++){
    int e = e0 + k*1024 + tid;
    if (e < E){
      int kk = key[e];
      int p = atomicAdd(&run[kk >> BSHIFT], 1);
      int2 pr; pr.x = pay[e]; pr.y = kk;
      pair[p] = pr;
    }
  }
}

// ---------------- counting-sort pass B: per-bucket local offsets + CSR fill ----------------

__global__ __launch_bounds__(256) void k_binB2(
    const int2* __restrict__ pair, const int* __restrict__ boff,
    int* __restrict__ offsets, int* __restrict__ csr_out, int N){
  __shared__ int cnt[BDR];
  __shared__ int scn[BDR];
  int base = blockIdx.x << BSHIFT;
  int hi = base + BDR; if (hi > N) hi = N;
  int nloc = hi - base;
  if (nloc <= 0) return;
  int tid = threadIdx.x;
  if (tid < BDR) cnt[tid] = 0;
  __syncthreads();
  int p0 = boff[blockIdx.x], p1 = boff[blockIdx.x+1];
  for (int p = p0 + tid; p < p1; p += 256) atomicAdd(&cnt[pair[p].y - base], 1);
  __syncthreads();
  int val = (tid < BDR) ? cnt[tid] : 0;
  if (tid < BDR) scn[tid] = val;
  __syncthreads();
  for (int off=1; off<BDR; off<<=1){
    int t = (tid >= off && tid < BDR) ? scn[tid-off] : 0;
    __syncthreads();
    if (tid < BDR) scn[tid] += t;
    __syncthreads();
  }
  if (tid < nloc){
    int o = p0 + scn[tid] - val;
    offsets[base + tid] = o;
    cnt[tid] = o;
  }
  __syncthreads();
  for (int p = p0 + tid; p < p1; p += 256){
    int2 pr = pair[p];
    int slot = atomicAdd(&cnt[pr.y - base], 1);
    csr_out[slot] = pr.x;
  }
}

// ---------------- pack pos+type into one float4 ----------------

__global__ void k_pack(const float* __restrict__ pos, const int* __restrict__ types,
                       float4* __restrict__ ptyp, int N){
  int i = blockIdx.x*256 + threadIdx.x;
  if (i >= N) return;
  float4 f; f.x = pos[3*i]; f.y = pos[3*i+1]; f.z = pos[3*i+2]; f.w = __int_as_float(types[i]);
  ptyp[i] = f;
}

// ---------------- radial-MLP evaluation (builder only) ----------------

__device__ __forceinline__ void radial_mlp(
    float r, int td, int ts, const float* sEmb,
    const float* sW1, const float* sW2, float* w_out /*9*/){
  float ee[18];
  #pragma unroll
  for (int i=0;i<4;i++){ ee[i] = sEmb[td*4+i]; ee[4+i] = sEmb[ts*4+i]; }
  float rm = fmaxf(r, 1e-9f);
  float inv = 1.f/rm;
  float xx = r * 0.2f;
  float x2v = xx*xx, x3v = x2v*xx, x6 = x3v*x3v, x7 = x6*xx, x8 = x7*xx;
  float env = 1.f - 28.f*x6 + 48.f*x7 - 21.f*x8;
  const float bc = 0.6324555320336759f;
  float pref = bc * env * inv;
  const float PI = 3.14159265358979323846f;
  float s1, cth;
  __sincosf(PI*xx, &s1, &cth);
  float two_c = 2.f*cth;
  float sp = 0.f, sc = s1;
  ee[8] = pref * sc;
  #pragma unroll
  for (int n=2;n<=10;n++){
    float sn = two_c*sc - sp;
    sp = sc; sc = sn;
    ee[7+n] = pref * sc;
  }
  float h[10];
  #pragma unroll
  for (int j=0;j<10;j++){
    float a = 0.f;
    #pragma unroll
    for (int k=0;k<18;k++) a = fmaf(ee[k], sW1[k*10+j], a);
    h[j] = fmaxf(a, 0.f);
  }
  #pragma unroll
  for (int sj=0;sj<9;sj++){
    float a = 0.f;
    #pragma unroll
    for (int j=0;j<10;j++) a = fmaf(h[j], sW2[j*9+sj], a);
    w_out[sj] = a;
  }
}

// ---------------- merged table: 32 u32/rec = {w1(v,d)x9, w2(v,d)x9, w3(v,d)x9, pad5} ----------------

__global__ __launch_bounds__(256) void k_mktab(
    const float* __restrict__ embed,
    const float* __restrict__ w1a, const float* __restrict__ w2a,
    const float* __restrict__ w1b, const float* __restrict__ w2b,
    const float* __restrict__ w1c, const float* __restrict__ w2c,
    uint32* __restrict__ tab){
  __shared__ float sEmb[16];
  __shared__ float sW1a[180], sW2a[90], sW1b[180], sW2b[90], sW1c[180], sW2c[90];
  int t = threadIdx.x;
  if (t < 16) sEmb[t] = embed[t];
  if (t < 180){ sW1a[t] = w1a[t]; sW1b[t] = w1b[t]; sW1c[t] = w1c[t]; }
  if (t < 90){  sW2a[t] = w2a[t]; sW2b[t] = w2b[t]; sW2c[t] = w2c[t]; }
  __syncthreads();
  int gid = blockIdx.x*256 + t;
  if (gid >= 16*TBINS) return;
  int combo = gid / TBINS, bin = gid - combo*TBINS;
  int td = combo >> 2, ts = combo & 3;
  const float dR = RMAX / TBINS;
  float r0 = bin*dR, r1 = r0 + dR;
  float a0[9], a1[9], b0[9], b1[9], c0[9], c1[9];
  radial_mlp(r0, td, ts, sEmb, sW1a, sW2a, a0);
  radial_mlp(r1, td, ts, sEmb, sW1a, sW2a, a1);
  radial_mlp(r0, td, ts, sEmb, sW1b, sW2b, b0);
  radial_mlp(r1, td, ts, sEmb, sW1b, sW2b, b1);
  radial_mlp(r0, td, ts, sEmb, sW1c, sW2c, c0);
  radial_mlp(r1, td, ts, sEmb, sW1c, sW2c, c1);
  uint32* rec = tab + (size_t)gid*32;
  #pragma unroll
  for (int s=0;s<9;s++){
    rec[s]    = pack_bf16(a0[s], a1[s]-a0[s]);
    rec[9+s]  = pack_bf16(b0[s], b1[s]-b0[s]);
    rec[18+s] = pack_bf16(c0[s], c1[s]-c0[s]);
  }
  #pragma unroll
  for (int s=27;s<32;s++) rec[s] = 0u;
}

// ---------------- layer 1+2 edge pass: Z->x1, bf16 shw2 (AoS records) ----------------

__global__ __launch_bounds__(256) void k_layer12t(
    const int* __restrict__ offsets, const int* __restrict__ csr_src,
    const float4* __restrict__ ptyp, const float* __restrict__ embed,
    const uint32* __restrict__ tab, const float* __restrict__ tp1,
    float* __restrict__ x1, uint32* __restrict__ shwb, int N){
  __shared__ float sT[36*92];
  __shared__ float sEmb[16];
  int t = threadIdx.x;
  if (t < 16) sEmb[t] = embed[t];
  for (int i=t; i<36*92; i+=256) sT[i] = tp1[i]*0.25f;
  __syncthreads();
  int gid = blockIdx.x*256 + t;
  int n = gid >> 2, q = gid & 3;
  if (n >= N) return;
  float4 fd = ptyp[n];
  float dx = fd.x, dy = fd.y, dz = fd.z;
  int td = __float_as_int(fd.w);
  const float c1 = 1.7320508075688772f, c2 = 3.872983346207417f, c2b = 1.118033988749895f;
  const float invD = (float)TBINS / RMAX;
  float Z[36];
  #pragma unroll
  for (int i=0;i<36;i++) Z[i]=0.f;
  int b0 = offsets[n], b1 = offsets[n+1];
  for (int j=b0+q; j<b1; j+=4){
    int s = csr_src[j];
    float4 fs = ptyp[s];
    float px = dx - fs.x, py = dy - fs.y, pz = dz - fs.z;
    int ts_ = __float_as_int(fs.w);
    float r = sqrtf(px*px + py*py + pz*pz);
    float inv = 1.f/fmaxf(r, 1e-9f);
    float ux = px*inv, uy = py*inv, uz = pz*inv;
    float sh[9];
    sh[0]=1.f; sh[1]=c1*uy; sh[2]=c1*uz; sh[3]=c1*ux;
    sh[4]=c2*ux*uy; sh[5]=c2*uy*uz; sh[6]=c2b*(3.f*uz*uz-1.f); sh[7]=c2*ux*uz;
    sh[8]=0.5f*c2*(ux*ux-uy*uy);
    float tt = r * invD;
    int bb = (int)tt; bb = (bb > TBINS-1) ? TBINS-1 : bb;
    float frac = tt - (float)bb;
    const uint32* rec = tab + ((size_t)((td*4+ts_)*TBINS + bb))*32;
    uint32 R[20];
    #pragma unroll
    for (int i=0;i<5;i++) *(uint4*)&R[i*4] = *(const uint4*)(rec + i*4);
    float x0[4];
    #pragma unroll
    for (int i=0;i<4;i++) x0[i] = sEmb[ts_*4+i];
    float sw2[9];
    #pragma unroll
    for (int sj=0;sj<9;sj++){
      uint32 ua = R[sj], ub = R[9+sj];
      float w1v = fmaf(frac, bf_hi(ua), bf_lo(ua));
      float w2v = fmaf(frac, bf_hi(ub), bf_lo(ub));
      float s1v = sh[sj]*w1v;
      sw2[sj] = sh[sj]*w2v;
      #pragma unroll
      for (int i=0;i<4;i++) Z[sj*4+i] = fmaf(s1v, x0[i], Z[sj*4+i]);
    }
    uint32* so = shwb + (size_t)j*5;
    so[0]=pack_bf16(sw2[0],sw2[1]); so[1]=pack_bf16(sw2[2],sw2[3]);
    so[2]=pack_bf16(sw2[4],sw2[5]); so[3]=pack_bf16(sw2[6],sw2[7]);
    so[4]=pack_bf16(sw2[8],0.f);
  }
  #pragma unroll
  for (int m=1; m<=2; m<<=1){
    #pragma unroll
    for (int i=0;i<36;i++) Z[i] += __shfl_xor(Z[i], m, 4);
  }
  float* xo = x1 + (size_t)n*76;
  int gi_prev = -1; float ga = 0.f;
  for (int cc=q*19; cc<q*19+19; cc++){
    float v;
    if (cc < 12){
      float y = 0.f;
      #pragma unroll
      for (int p=0;p<36;p++) y = fmaf(Z[p], sT[p*92+cc], y);
      v = (cc<4) ? (fmaxf(y,0.f) + sEmb[td*4+cc]) : fabsf(y);
    } else {
      int j = cc - 12;
      int gi = (j<24) ? (j/3) : (8 + (j-24)/5);
      if (gi != gi_prev){
        float gy = 0.f;
        #pragma unroll
        for (int p=0;p<36;p++) gy = fmaf(Z[p], sT[p*92+12+gi], gy);
        ga = (gi<4 || (gi>=8 && gi<12)) ? fmaxf(gy,0.f) : tanhf(gy);
        gi_prev = gi;
      }
      float y = 0.f;
      #pragma unroll
      for (int p=0;p<36;p++) y = fmaf(Z[p], sT[p*92+28+j], y);
      v = y*ga;
    }
    xo[cc] = v;
  }
}

// ---------------- cast x1 -> bf16 pairs ----------------

__global__ void k_cast(const float* __restrict__ x1, uint32* __restrict__ x1b, int n38){
  int i = blockIdx.x*256 + threadIdx.x;
  if (i >= n38) return;
  float2 f = *(const float2*)&x1[(size_t)i*2];
  x1b[i] = pack_bf16(f.x, f.y);
}

// ---------------- layer 2 stage A ----------------

__global__ __launch_bounds__(256) void k_conv2c(
    const int* __restrict__ offsets, const int* __restrict__ csr_src,
    const uint32* __restrict__ shwb, const uint32* __restrict__ x1b,
    uint32* __restrict__ Z2u, int d0, int dend){
  int g = blockIdx.x*256 + threadIdx.x;
  int dg = g/38;
  int u = g - dg*38;
  int d = d0 + dg;
  if (d >= dend) return;
  float z[9], zb[9];
  #pragma unroll
  for (int s=0;s<9;s++){ z[s]=0.f; zb[s]=0.f; }
  int b0 = offsets[d], b1 = offsets[d+1];
  for (int j=b0;j<b1;j++){
    int sn = csr_src[j];
    uint32 xv = x1b[(size_t)sn*38 + u];
    float xa = bf_lo(xv), xb = bf_hi(xv);
    const uint32* sw = shwb + (size_t)j*5;
    uint32 a0=sw[0], a1=sw[1], a2=sw[2], a3=sw[3], a4=sw[4];
    float w[9];
    w[0]=bf_lo(a0); w[1]=bf_hi(a0); w[2]=bf_lo(a1); w[3]=bf_hi(a1);
    w[4]=bf_lo(a2); w[5]=bf_hi(a2); w[6]=bf_lo(a3); w[7]=bf_hi(a3); w[8]=bf_lo(a4);
    #pragma unroll
    for (int s=0;s<9;s++){
      z[s]  = fmaf(w[s], xa, z[s]);
      zb[s] = fmaf(w[s], xb, zb[s]);
    }
  }
  uint32* zr = Z2u + (size_t)dg*352;
  #pragma unroll
  for (int s=0;s<9;s++) zr[s*38+u] = pack_bf16(z[s], zb[s]);
  if (u < 10) zr[342+u] = 0u;
}

// ---------------- W transpose-pack for MFMA ----------------

__global__ void k_wprep2(const float* __restrict__ tp2, unsigned short* __restrict__ Wt){
  int q = blockIdx.x*256 + threadIdx.x;
  if (q >= 22*96*32) return;
  int kin = q & 31;
  int rest = q >> 5;
  int col = rest % 96, s = rest / 96;
  int k = s*32 + kin;
  float v = (k < 684 && col < 92) ? tp2[k*92+col]*0.25f : 0.f;
  __hip_bfloat16 b = __float2bfloat16(v);
  Wt[q] = *reinterpret_cast<unsigned short*>(&b);
}

// ---------------- layer 2 stage B: MFMA GEMM + gate + residual + fused A ----------------

__global__ __launch_bounds__(256) void k_gemm2m(
    const uint32* __restrict__ Z2u, const unsigned short* __restrict__ Wt,
    const float* __restrict__ x1, const float* __restrict__ tp3,
    float* __restrict__ A, int d0, int dend){
  __shared__ float lw[64][100];
  __shared__ float tl3[684];
  int t = threadIdx.x;
  for (int i=t;i<684;i+=256) tl3[i] = tp3[i]*0.25f;
  int w = t >> 6, l = t & 63;
  int lrow = l & 15, lk = l >> 4;
  int mb = blockIdx.x*64;
  const uint32* arow = Z2u + (size_t)(mb + w*16 + lrow)*352 + lk*4;
  const short8* bb = (const short8*)Wt;
  int boff = lrow*4 + lk;
  f32x4 acc[6];
  #pragma unroll
  for (int ct=0;ct<6;ct++) acc[ct] = (f32x4){0.f,0.f,0.f,0.f};
  for (int s=0;s<22;s++){
    short8 af = *(const short8*)(arow + s*16);
    #pragma unroll
    for (int ct=0;ct<6;ct++){
      short8 bf = bb[(s*96 + ct*16)*4 + boff];
      acc[ct] = __builtin_amdgcn_mfma_f32_16x16x32_bf16(af, bf, acc[ct], 0, 0, 0);
    }
  }
  #pragma unroll
  for (int ct=0;ct<6;ct++)
    #pragma unroll
    for (int i=0;i<4;i++)
      lw[w*16 + lk*4 + i][ct*16 + lrow] = acc[ct][i];
  __syncthreads();
  int m = t>>2, q = t&3;
  int node = d0 + mb + m;
  float pA[9];
  #pragma unroll
  for (int s=0;s<9;s++) pA[s]=0.f;
  if (node < dend){
    const float* xr = x1 + (size_t)node*76;
    for (int cc=q*19; cc<q*19+19; cc++){
      float v;
      if (cc < 12){
        float y = lw[m][cc];
        v = (cc<4) ? fmaxf(y,0.f) : fabsf(y);
      } else {
        int j = cc-12;
        int gi = (j<24) ? (j/3) : (8 + (j-24)/5);
        float gy = lw[m][12+gi];
        float ga = (gi<4 || (gi>=8 && gi<12)) ? fmaxf(gy,0.f) : tanhf(gy);
        v = lw[m][28+j]*ga;
      }
      float xv = v + xr[cc];
      #pragma unroll
      for (int s=0;s<9;s++) pA[s] = fmaf(xv, tl3[s*76+cc], pA[s]);
    }
  }
  #pragma unroll
  for (int off=1; off<=2; off<<=1){
    #pragma unroll
    for (int s=0;s<9;s++) pA[s] += __shfl_xor(pA[s], off, 4);
  }
  if (node < dend && q == 0){
    float* Ar = A + (size_t)node*16;
    float4 w0 = {pA[0],pA[1],pA[2],pA[3]};
    float4 w1 = {pA[4],pA[5],pA[6],pA[7]};
    *(float4*)Ar = w0;
    *(float4*)(Ar+4) = w1;
    Ar[8] = pA[8];
  }
}

// ---------------- layer 3: G[n] over src-CSR (L2-resident gathers only) ----------------

__global__ __launch_bounds__(256) void k_g3t(
    const int* __restrict__ off2, const int* __restrict__ csr2_dst,
    const float4* __restrict__ ptyp, const uint32* __restrict__ tab,
    float* __restrict__ G, int N){
  int gid = blockIdx.x*256 + threadIdx.x;
  int n = gid >> 2, q = gid & 3;
  if (n >= N) return;
  float acc[9];
  #pragma unroll
  for (int s=0;s<9;s++) acc[s]=0.f;
  float4 fs = ptyp[n];
  float sx = fs.x, sy = fs.y, sz = fs.z;
  int ts_ = __float_as_int(fs.w);
  const float c1 = 1.7320508075688772f, c2 = 3.872983346207417f, c2b = 1.118033988749895f;
  const float invD = (float)TBINS / RMAX;
  int b0 = off2[n], b1 = off2[n+1];
  for (int j=b0+q; j<b1; j+=4){
    int d = csr2_dst[j];
    float4 fdd = ptyp[d];
    float px = fdd.x-sx, py = fdd.y-sy, pz = fdd.z-sz;
    int td_ = __float_as_int(fdd.w);
    float r = sqrtf(px*px + py*py + pz*pz);
    float inv = 1.f/fmaxf(r, 1e-9f);
    float ux = px*inv, uy = py*inv, uz = pz*inv;
    float sh[9];
    sh[0]=1.f; sh[1]=c1*uy; sh[2]=c1*uz; sh[3]=c1*ux;
    sh[4]=c2*ux*uy; sh[5]=c2*uy*uz; sh[6]=c2b*(3.f*uz*uz-1.f); sh[7]=c2*ux*uz;
    sh[8]=0.5f*c2*(ux*ux-uy*uy);
    float tt = r * invD;
    int bb = (int)tt; bb = (bb > TBINS-1) ? TBINS-1 : bb;
    float frac = tt - (float)bb;
    const uint32* rec = tab + ((size_t)((td_*4+ts_)*TBINS + bb))*32;
    uint32 R[12];
    #pragma unroll
    for (int i=0;i<3;i++) *(uint4*)&R[i*4] = *(const uint4*)(rec + 16 + i*4);
    #pragma unroll
    for (int sj=0;sj<9;sj++){
      uint32 u = R[2+sj];
      float w = fmaf(frac, bf_hi(u), bf_lo(u));
      acc[sj] = fmaf(sh[sj], w, acc[sj]);
    }
  }
  #pragma unroll
  for (int off=2; off>0; off>>=1){
    #pragma unroll
    for (int s=0;s<9;s++) acc[s] += __shfl_down(acc[s], off, 4);
  }
  if (q == 0){
    float* gr = G + (size_t)n*12;
    float4 w0 = {acc[0],acc[1],acc[2],acc[3]};
    float4 w1 = {acc[4],acc[5],acc[6],acc[7]};
    *(float4*)gr = w0;
    *(float4*)(gr+4) = w1;
    gr[8] = acc[8];
  }
}

// ---------------- layer 3 finish: streaming dot(G, A) ----------------

__global__ __launch_bounds__(256) void k_finalG(
    const float* __restrict__ G, const float* __restrict__ A,
    float* __restrict__ out, int N){
  int n = blockIdx.x*256 + threadIdx.x;
  float part = 0.f;
  if (n < N){
    const float* gr = G + (size_t)n*12;
    const float* Ar = A + (size_t)n*16;
    float4 g0 = *(const float4*)gr, g1 = *(const float4*)(gr+4);
    float4 a0 = *(const float4*)Ar, a1 = *(const float4*)(Ar+4);
    part = g0.x*a0.x + g0.y*a0.y + g0.z*a0.z + g0.w*a0.w
         + g1.x*a1.x + g1.y*a1.y + g1.z*a1.z + g1.w*a1.w
         + gr[8]*Ar[8];
  }
  #pragma unroll
  for (int off=32; off>0; off>>=1) part += __shfl_down(part, off, 64);
  if ((threadIdx.x & 63) == 0) atomicAdd(out, part);
}

// ---------------- launch ----------------

extern "C" void kernel_launch(void* const* d_in, const int* in_sizes, int n_in,
                              void* d_out, int out_size, void* d_ws, size_t ws_size,
                              hipStream_t stream){
  const int*   types = (const int*)d_in[0];
  const float* pos   = (const float*)d_in[1];
  const int*   esrc  = (const int*)d_in[2];
  const int*   edst  = (const int*)d_in[3];
  const float* embed = (const float*)d_in[4];
  const float* m1w1=(const float*)d_in[5],  *m1w2=(const float*)d_in[6],  *tp1=(const float*)d_in[7];
  const float* m2w1=(const float*)d_in[8],  *m2w2=(const float*)d_in[9],  *tp2=(const float*)d_in[10];
  const float* m3w1=(const float*)d_in[11], *m3w2=(const float*)d_in[12], *tp3=(const float*)d_in[13];
  int N = in_sizes[0];
  int E = in_sizes[2];
  float* out = (float*)d_out;

  char* wsb = (char*)d_ws; size_t off = 0;
  auto alloc = [&](size_t b)->char*{ char* p = wsb + off; off = (off + b + 255) & ~(size_t)255; return p; };
  float*  x1      = (float*)alloc((size_t)N*76*sizeof(float));
  uint32* x1b     = (uint32*)alloc((size_t)N*38*sizeof(uint32));
  float4* ptyp    = (float4*)alloc((size_t)N*sizeof(float4));
  uint32* shwb    = (uint32*)alloc((size_t)E*5*sizeof(uint32));
  int*    csr_src = (int*)alloc((size_t)E*sizeof(int));
  int*    csr2_dst= (int*)alloc((size_t)E*sizeof(int));
  int2*   pair    = (int2*)alloc((size_t)E*sizeof(int2));
  int*    offsets = (int*)alloc((size_t)(N+1)*sizeof(int));
  int*    off2    = (int*)alloc((size_t)(N+1)*sizeof(int));
  int*    gb1     = (int*)alloc(1024*sizeof(int));
  int*    gb2     = (int*)alloc(1024*sizeof(int));
  int*    boff1   = (int*)alloc(1025*sizeof(int));
  int*    boff2   = (int*)alloc(1025*sizeof(int));
  int*    gcur1   = (int*)alloc(1024*sizeof(int));
  int*    gcur2   = (int*)alloc(1024*sizeof(int));
  unsigned short* Wt = (unsigned short*)alloc((size_t)22*96*32*sizeof(unsigned short));
  float*  A       = (float*)alloc((size_t)N*16*sizeof(float));
  float*  G       = (float*)alloc((size_t)N*12*sizeof(float));
  uint32* tab     = (uint32*)alloc((size_t)16*TBINS*32*sizeof(uint32));

  // elastic bf16 Z2 chunk
  size_t avail = (ws_size > off) ? (ws_size - off - 512) : 0;
  long long rows = (long long)(avail / (352*sizeof(uint32))) - 64;
  int CH = (rows > 50176) ? 50176 : (int)rows;
  CH = (CH / 64) * 64;
  if (CH < 64) CH = 64;
  uint32* Z2u = (uint32*)alloc((size_t)(CH+64)*352*sizeof(uint32));

  hipMemsetAsync(gb1, 0, 2048*sizeof(int), stream);   // gb1 | gb2 contiguous
  hipMemsetAsync(out, 0, sizeof(float), stream);

  int nbN = (N+255)/256;
  int nbT = (16*TBINS+255)/256;
  int NBUCK = (N + BDR - 1) >> BSHIFT;
  int nbC = (E+8191)/8192;
  k_pack<<<nbN,256,0,stream>>>(pos, types, ptyp, N);
  k_mktab<<<nbT,256,0,stream>>>(embed, m1w1, m1w2, m2w1, m2w2, m3w1, m3w2, tab);
  // bucket histogram (both keys) + bucket scan
  k_bcount<<<nbC,1024,0,stream>>>(esrc, edst, gb1, gb2, E);
  k_bscan<<<1,1024,0,stream>>>(gb1, gb2, boff1, boff2, gcur1, gcur2,
                               offsets, off2, N, E, NBUCK);
  // dest-CSR (key=edst, payload=esrc)
  k_binA<<<nbC,1024,0,stream>>>(edst, esrc, gcur1, pair, E, NBUCK);
  k_binB2<<<NBUCK,256,0,stream>>>(pair, boff1, offsets, csr_src, N);
  // src-CSR (key=esrc, payload=edst)
  k_binA<<<nbC,1024,0,stream>>>(esrc, edst, gcur2, pair, E, NBUCK);
  k_binB2<<<NBUCK,256,0,stream>>>(pair, boff2, off2, csr2_dst, N);

  k_wprep2<<<(22*96*32+255)/256,256,0,stream>>>(tp2, Wt);

  // layer 3 geometry part (independent of layers 1-2)
  k_g3t<<<(4*N+255)/256,256,0,stream>>>(off2, csr2_dst, ptyp, tab, G, N);

  // layer 1 + layer-2 shw (single fused edge pass, merged table)
  k_layer12t<<<(4*N+255)/256,256,0,stream>>>(offsets, csr_src, ptyp, embed,
                                             tab, tp1, x1, shwb, N);
  k_cast<<<(N*38+255)/256,256,0,stream>>>(x1, x1b, N*38);

  // layer 2 (+ fused A epilogue; x2 never materialized)
  for (int d0 = 0; d0 < N; d0 += CH){
    int dend = (d0 + CH < N) ? (d0 + CH) : N;
    int nn = dend - d0;
    k_conv2c<<<((nn*38)+255)/256,256,0,stream>>>(offsets, csr_src, shwb, x1b, Z2u, d0, dend);
    k_gemm2m<<<(nn+63)/64,256,0,stream>>>(Z2u, Wt, x1, tp3, A, d0, dend);
  }

  // layer 3 finish: streaming dot
  k_finalG<<<nbN,256,0,stream>>>(G, A, out, N);
}